// Round 1
// baseline (122.838 us; speedup 1.0000x reference)
//
#include <hip/hip_runtime.h>

#define B_ROWS 1048576
#define K_CODES 16
#define D_DIM 64

constexpr int BLOCK = 256;
constexpr int GRID  = 2048;   // 32768 row-groups/iter, 32 iters over B

__global__ __launch_bounds__(BLOCK)
void vq_main(const float* __restrict__ z,
             const float* __restrict__ emb,
             float* __restrict__ out_q,
             float* __restrict__ out_idx,
             float* __restrict__ partials)
{
    __shared__ __align__(16) float s_emb[K_CODES * D_DIM];  // 4 KB
    __shared__ float s_se[K_CODES];
    __shared__ float s_w[BLOCK / 64];

    const int t = threadIdx.x;

    // stage embedding into LDS (1024 floats, 256 threads x float4)
    ((float4*)s_emb)[t] = ((const float4*)emb)[t];
    __syncthreads();

    // ||e_k||^2 per code (f32 sequential; enters d at magnitude ~64, rounding-insensitive)
    if (t < K_CODES) {
        float s = 0.f;
        #pragma unroll
        for (int c = 0; c < D_DIM; ++c) {
            float e = s_emb[t * D_DIM + c];
            s = fmaf(e, e, s);
        }
        s_se[t] = s;
    }
    __syncthreads();

    const int j = t & 15;                 // lane-in-group = column chunk
    // per-lane embedding columns: e[k][j*4 .. j*4+3], k = 0..15  (64 VGPRs)
    float4 ereg[16];
    #pragma unroll
    for (int k = 0; k < 16; ++k)
        ereg[k] = *(const float4*)&s_emb[k * D_DIM + j * 4];
    const float se_j = s_se[j];           // lane j will own k == j after reduce

    float lossacc = 0.f;

    const int gid    = (blockIdx.x * BLOCK + t) >> 4;   // global row-group id
    const int stride = (GRID * BLOCK) >> 4;             // 32768

    for (int row = gid; row < B_ROWS; row += stride) {
        const float4 zv = *(const float4*)&z[(size_t)row * D_DIM + j * 4];

        // partial dots for all 16 codes over this lane's 4 columns
        float p[16];
        #pragma unroll
        for (int k = 0; k < 16; ++k) {
            float4 e = ereg[k];
            p[k] = fmaf(zv.w, e.w, fmaf(zv.z, e.z, fmaf(zv.y, e.y, zv.x * e.x)));
        }
        // ||z||^2 partial + 16-lane tree reduce
        float szp = fmaf(zv.w, zv.w, fmaf(zv.z, zv.z, fmaf(zv.y, zv.y, zv.x * zv.x)));
        szp += __shfl_xor(szp, 8, 64);
        szp += __shfl_xor(szp, 4, 64);
        szp += __shfl_xor(szp, 2, 64);
        szp += __shfl_xor(szp, 1, 64);

        // bisection transpose-reduce: lane j ends with dot(z, e_j)
        bool hi = (j & 8) != 0;
        float r8[8];
        #pragma unroll
        for (int i = 0; i < 8; ++i) {
            float sendv = hi ? p[i] : p[i + 8];
            float keepv = hi ? p[i + 8] : p[i];
            r8[i] = keepv + __shfl_xor(sendv, 8, 64);
        }
        hi = (j & 4) != 0;
        float r4[4];
        #pragma unroll
        for (int i = 0; i < 4; ++i) {
            float sendv = hi ? r8[i] : r8[i + 4];
            float keepv = hi ? r8[i + 4] : r8[i];
            r4[i] = keepv + __shfl_xor(sendv, 4, 64);
        }
        hi = (j & 2) != 0;
        float r2[2];
        #pragma unroll
        for (int i = 0; i < 2; ++i) {
            float sendv = hi ? r2[i] : r4[i + 2];   // placeholder fixed below
            (void)sendv;
        }
        // (explicit to avoid any indexing subtlety)
        {
            float sendv0 = hi ? r4[0] : r4[2];
            float keepv0 = hi ? r4[2] : r4[0];
            r2[0] = keepv0 + __shfl_xor(sendv0, 2, 64);
            float sendv1 = hi ? r4[1] : r4[3];
            float keepv1 = hi ? r4[3] : r4[1];
            r2[1] = keepv1 + __shfl_xor(sendv1, 2, 64);
        }
        hi = (j & 1) != 0;
        float dot;
        {
            float sendv = hi ? r2[0] : r2[1];
            float keepv = hi ? r2[1] : r2[0];
            dot = keepv + __shfl_xor(sendv, 1, 64);
        }

        // distance, f32-rounded exactly like ref: (sz + se) - 2*dot
        const float tt = szp + se_j;
        const float d  = tt - 2.0f * dot;

        // argmin over 16 lanes, first-occurrence tie-break (matches np.argmin)
        float vmin = d;
        vmin = fminf(vmin, __shfl_xor(vmin, 1, 64));
        vmin = fminf(vmin, __shfl_xor(vmin, 2, 64));
        vmin = fminf(vmin, __shfl_xor(vmin, 4, 64));
        vmin = fminf(vmin, __shfl_xor(vmin, 8, 64));
        unsigned long long bal = __ballot(d == vmin);
        unsigned int mask = (unsigned int)((bal >> (t & 48)) & 0xFFFFull);
        int kmin = __ffs(mask) - 1;

        // quantized chunk from LDS embedding
        const float4 qv = *(const float4*)&s_emb[kmin * D_DIM + j * 4];

        // loss partial
        float dx = zv.x - qv.x; lossacc = fmaf(dx, dx, lossacc);
        dx = zv.y - qv.y;       lossacc = fmaf(dx, dx, lossacc);
        dx = zv.z - qv.z;       lossacc = fmaf(dx, dx, lossacc);
        dx = zv.w - qv.w;       lossacc = fmaf(dx, dx, lossacc);

        *(float4*)&out_q[(size_t)row * D_DIM + j * 4] = qv;
        if (j == 0) out_idx[row] = (float)kmin;
    }

    // block loss reduction (deterministic)
    lossacc += __shfl_xor(lossacc, 32, 64);
    lossacc += __shfl_xor(lossacc, 16, 64);
    lossacc += __shfl_xor(lossacc, 8, 64);
    lossacc += __shfl_xor(lossacc, 4, 64);
    lossacc += __shfl_xor(lossacc, 2, 64);
    lossacc += __shfl_xor(lossacc, 1, 64);
    if ((t & 63) == 0) s_w[t >> 6] = lossacc;
    __syncthreads();
    if (t == 0) partials[blockIdx.x] = (s_w[0] + s_w[1]) + (s_w[2] + s_w[3]);
}

__global__ void vq_finalize(const float* __restrict__ partials, int n,
                            float* __restrict__ out_loss)
{
    __shared__ float sw[4];
    float s = 0.f;
    for (int i = threadIdx.x; i < n; i += 256) s += partials[i];
    s += __shfl_xor(s, 32, 64);
    s += __shfl_xor(s, 16, 64);
    s += __shfl_xor(s, 8, 64);
    s += __shfl_xor(s, 4, 64);
    s += __shfl_xor(s, 2, 64);
    s += __shfl_xor(s, 1, 64);
    if ((threadIdx.x & 63) == 0) sw[threadIdx.x >> 6] = s;
    __syncthreads();
    if (threadIdx.x == 0) {
        float tot = (sw[0] + sw[1]) + (sw[2] + sw[3]);
        // vq_loss = 1.25 * mean; 1.25 / 2^26 is exact in f32
        *out_loss = tot * (1.25f / (float)(B_ROWS * (size_t)D_DIM));
    }
}

extern "C" void kernel_launch(void* const* d_in, const int* in_sizes, int n_in,
                              void* d_out, int out_size, void* d_ws, size_t ws_size,
                              hipStream_t stream)
{
    const float* z   = (const float*)d_in[0];
    const float* emb = (const float*)d_in[1];
    float* out      = (float*)d_out;
    float* out_q    = out;                                  // [B,64]
    float* out_idx  = out + (size_t)B_ROWS * D_DIM;         // [B]
    float* out_loss = out_idx + B_ROWS;                     // [1]
    float* partials = (float*)d_ws;                         // GRID floats

    vq_main<<<GRID, BLOCK, 0, stream>>>(z, emb, out_q, out_idx, partials);
    vq_finalize<<<1, 256, 0, stream>>>(partials, GRID, out_loss);
}

// Round 2
// 114.168 us; speedup vs baseline: 1.0759x; 1.0759x over previous
//
#include <hip/hip_runtime.h>

#define B_ROWS 1048576
#define K_CODES 16
#define D_DIM 64

constexpr int BLOCK = 256;
constexpr int GRID  = 2048;   // 32768 row-groups/iter, exactly 32 iters over B

// --- cross-lane helpers: xor1/xor2 on the VALU (DPP quad_perm), xor4/xor8 on DS swizzle ---
__device__ __forceinline__ float xor1_dpp(float x) {
    return __builtin_bit_cast(float,
        __builtin_amdgcn_update_dpp(0, __builtin_bit_cast(int, x), 0xB1 /*quad_perm [1,0,3,2]*/,
                                    0xF, 0xF, true));
}
__device__ __forceinline__ float xor2_dpp(float x) {
    return __builtin_bit_cast(float,
        __builtin_amdgcn_update_dpp(0, __builtin_bit_cast(int, x), 0x4E /*quad_perm [2,3,0,1]*/,
                                    0xF, 0xF, true));
}
__device__ __forceinline__ float xor4_sw(float x) {
    return __builtin_bit_cast(float,
        __builtin_amdgcn_ds_swizzle(__builtin_bit_cast(int, x), 0x101F)); // BitMode xor=4
}
__device__ __forceinline__ float xor8_sw(float x) {
    return __builtin_bit_cast(float,
        __builtin_amdgcn_ds_swizzle(__builtin_bit_cast(int, x), 0x201F)); // BitMode xor=8
}

__global__ __launch_bounds__(BLOCK)
void vq_main(const float* __restrict__ z,
             const float* __restrict__ emb,
             float* __restrict__ out_q,
             float* __restrict__ out_idx,
             float* __restrict__ partials)
{
    __shared__ __align__(16) float s_emb[K_CODES * D_DIM];  // 4 KB
    __shared__ float s_se[K_CODES];
    __shared__ float s_w[BLOCK / 64];

    const int t = threadIdx.x;

    // stage embedding into LDS (1024 floats, 256 threads x float4)
    ((float4*)s_emb)[t] = ((const float4*)emb)[t];
    __syncthreads();

    // ||e_k||^2 per code, f32 sequential (same rounding path as before -> passed)
    if (t < K_CODES) {
        float s = 0.f;
        #pragma unroll
        for (int c = 0; c < D_DIM; ++c) {
            float e = s_emb[t * D_DIM + c];
            s = fmaf(e, e, s);
        }
        s_se[t] = s;
    }
    __syncthreads();

    const int j = t & 15;                 // lane-in-group = column chunk
    // permuted embedding registers: ereg[r] holds code (r ^ j)'s columns j*4..j*4+3.
    // This makes the butterfly transpose-reduce select-free (static register indices).
    float4 ereg[16];
    #pragma unroll
    for (int r = 0; r < 16; ++r)
        ereg[r] = *(const float4*)&s_emb[((r ^ j) * D_DIM) + j * 4];
    const float se_j = s_se[j];           // lane j ends owning code k == j

    float lossacc = 0.f;

    const int gid    = (blockIdx.x * BLOCK + t) >> 4;   // global row-group id
    const int stride = (GRID * BLOCK) >> 4;             // 32768

    int row = gid;
    float4 zv = *(const float4*)&z[(size_t)row * D_DIM + j * 4];

    while (row < B_ROWS) {
        // 1-deep prefetch of next row chunk (independent of the compute chain)
        const int nrow = row + stride;
        float4 zn = zv;
        if (nrow < B_ROWS)
            zn = *(const float4*)&z[(size_t)nrow * D_DIM + j * 4];

        // partial dots; p[r] = partial for code (r ^ j) over this lane's 4 columns
        float p[16];
        #pragma unroll
        for (int r = 0; r < 16; ++r) {
            float4 e = ereg[r];
            p[r] = fmaf(zv.w, e.w, fmaf(zv.z, e.z, fmaf(zv.y, e.y, zv.x * e.x)));
        }

        // ||z||^2 partial + 16-lane all-reduce (2 DPP + 2 swizzle)
        float szp = fmaf(zv.w, zv.w, fmaf(zv.z, zv.z, fmaf(zv.y, zv.y, zv.x * zv.x)));
        szp += xor1_dpp(szp);
        szp += xor2_dpp(szp);
        szp += xor4_sw(szp);
        szp += xor8_sw(szp);

        // select-free butterfly transpose-reduce: lane j ends with dot(z, e_j) in p[0].
        // Invariant: value(j, r) = partial for code (r ^ j); exchanging index (r ^ 2^b)
        // with lane (j ^ 2^b) pairs identical codes, so p[r] += shfl_xor(p[r^2^b], 2^b).
        #pragma unroll
        for (int r = 0; r < 16; r += 2)  p[r] += xor1_dpp(p[r + 1]);   // 8x DPP
        #pragma unroll
        for (int r = 0; r < 16; r += 4)  p[r] += xor2_dpp(p[r + 2]);   // 4x DPP
        #pragma unroll
        for (int r = 0; r < 16; r += 8)  p[r] += xor4_sw(p[r + 4]);    // 2x swizzle
        p[0] += xor8_sw(p[8]);                                         // 1x swizzle
        const float dot = p[0];

        // distance, f32-rounded exactly like ref: (||z||^2 + ||e_j||^2) - 2*dot
        const float d = (szp + se_j) - 2.0f * dot;

        // argmin over 16 lanes, first-occurrence tie-break (matches np.argmin)
        float vmin = d;
        vmin = fminf(vmin, xor1_dpp(vmin));
        vmin = fminf(vmin, xor2_dpp(vmin));
        vmin = fminf(vmin, xor4_sw(vmin));
        vmin = fminf(vmin, xor8_sw(vmin));
        unsigned long long bal = __ballot(d == vmin);
        unsigned int mask = (unsigned int)((bal >> (t & 48)) & 0xFFFFull);
        int kmin = __ffs(mask) - 1;

        // quantized chunk from LDS embedding (1 DS read)
        const float4 qv = *(const float4*)&s_emb[kmin * D_DIM + j * 4];

        // loss partial
        float dx = zv.x - qv.x; lossacc = fmaf(dx, dx, lossacc);
        dx = zv.y - qv.y;       lossacc = fmaf(dx, dx, lossacc);
        dx = zv.z - qv.z;       lossacc = fmaf(dx, dx, lossacc);
        dx = zv.w - qv.w;       lossacc = fmaf(dx, dx, lossacc);

        *(float4*)&out_q[(size_t)row * D_DIM + j * 4] = qv;
        if (j == 0) out_idx[row] = (float)kmin;

        zv  = zn;
        row = nrow;
    }

    // block loss reduction (deterministic)
    lossacc += __shfl_xor(lossacc, 32, 64);
    lossacc += __shfl_xor(lossacc, 16, 64);
    lossacc += __shfl_xor(lossacc, 8, 64);
    lossacc += __shfl_xor(lossacc, 4, 64);
    lossacc += __shfl_xor(lossacc, 2, 64);
    lossacc += __shfl_xor(lossacc, 1, 64);
    if ((t & 63) == 0) s_w[t >> 6] = lossacc;
    __syncthreads();
    if (t == 0) partials[blockIdx.x] = (s_w[0] + s_w[1]) + (s_w[2] + s_w[3]);
}

__global__ void vq_finalize(const float* __restrict__ partials, int n,
                            float* __restrict__ out_loss)
{
    __shared__ float sw[4];
    float s = 0.f;
    for (int i = threadIdx.x; i < n; i += 256) s += partials[i];
    s += __shfl_xor(s, 32, 64);
    s += __shfl_xor(s, 16, 64);
    s += __shfl_xor(s, 8, 64);
    s += __shfl_xor(s, 4, 64);
    s += __shfl_xor(s, 2, 64);
    s += __shfl_xor(s, 1, 64);
    if ((threadIdx.x & 63) == 0) sw[threadIdx.x >> 6] = s;
    __syncthreads();
    if (threadIdx.x == 0) {
        float tot = (sw[0] + sw[1]) + (sw[2] + sw[3]);
        // vq_loss = 1.25 * mean; 1.25 / 2^26 is exact in f32
        *out_loss = tot * (1.25f / (float)(B_ROWS * (size_t)D_DIM));
    }
}

extern "C" void kernel_launch(void* const* d_in, const int* in_sizes, int n_in,
                              void* d_out, int out_size, void* d_ws, size_t ws_size,
                              hipStream_t stream)
{
    const float* z   = (const float*)d_in[0];
    const float* emb = (const float*)d_in[1];
    float* out      = (float*)d_out;
    float* out_q    = out;                                  // [B,64]
    float* out_idx  = out + (size_t)B_ROWS * D_DIM;         // [B]
    float* out_loss = out_idx + B_ROWS;                     // [1]
    float* partials = (float*)d_ws;                         // GRID floats

    vq_main<<<GRID, BLOCK, 0, stream>>>(z, emb, out_q, out_idx, partials);
    vq_finalize<<<1, 256, 0, stream>>>(partials, GRID, out_loss);
}

// Round 4
// 107.657 us; speedup vs baseline: 1.1410x; 1.0605x over previous
//
#include <hip/hip_runtime.h>

#define B_ROWS 1048576
#define K_CODES 16
#define D_DIM 64

constexpr int BLOCK = 256;
constexpr int GRID  = 2048;   // 32768 row-groups/iter, exactly 32 iters over B

// native clang vector type — accepted by __builtin_nontemporal_load/store
typedef float f32x4 __attribute__((ext_vector_type(4)));

// --- cross-lane helpers, ALL on the VALU (DPP), zero DS-pipe ops ---
// masks {1,2,7,15} span GF(2)^4 -> complete 16-lane butterfly without ds_swizzle.
__device__ __forceinline__ float xor1_dpp(float x) {   // quad_perm [1,0,3,2]
    return __builtin_bit_cast(float,
        __builtin_amdgcn_update_dpp(0, __builtin_bit_cast(int, x), 0xB1, 0xF, 0xF, true));
}
__device__ __forceinline__ float xor2_dpp(float x) {   // quad_perm [2,3,0,1]
    return __builtin_bit_cast(float,
        __builtin_amdgcn_update_dpp(0, __builtin_bit_cast(int, x), 0x4E, 0xF, 0xF, true));
}
__device__ __forceinline__ float xor7_dpp(float x) {   // row_half_mirror: lane ^= 7
    return __builtin_bit_cast(float,
        __builtin_amdgcn_update_dpp(0, __builtin_bit_cast(int, x), 0x141, 0xF, 0xF, true));
}
__device__ __forceinline__ float xor15_dpp(float x) {  // row_mirror: lane ^= 15
    return __builtin_bit_cast(float,
        __builtin_amdgcn_update_dpp(0, __builtin_bit_cast(int, x), 0x140, 0xF, 0xF, true));
}

__global__ __launch_bounds__(BLOCK)
void vq_main(const float* __restrict__ z,
             const float* __restrict__ emb,
             float* __restrict__ out_q,
             float* __restrict__ out_idx,
             float* __restrict__ partials)
{
    __shared__ __align__(16) float s_emb[K_CODES * D_DIM];  // 4 KB
    __shared__ float s_se[K_CODES];
    __shared__ float s_w[BLOCK / 64];

    const int t = threadIdx.x;

    // stage embedding into LDS (1024 floats, 256 threads x float4)
    ((float4*)s_emb)[t] = ((const float4*)emb)[t];
    __syncthreads();

    // ||e_k||^2 per code, f32 sequential (identical rounding path to passing rounds)
    if (t < K_CODES) {
        float s = 0.f;
        #pragma unroll
        for (int c = 0; c < D_DIM; ++c) {
            float e = s_emb[t * D_DIM + c];
            s = fmaf(e, e, s);
        }
        s_se[t] = s;
    }
    __syncthreads();

    const int j = t & 15;                 // lane-in-group
    // Column relabeling sigma: lane j owns column chunk sj. Linear over GF(2) with
    // sigma(1)=8, sigma(2)=4, sigma(4)=14, sigma(8)=3  =>  sigma(15)=1, sigma(7)=2.
    // Stage order (15,7,2,1) then pairs column-bits (0,1,2,3): the dot tree is
    // bitwise identical to the previous (passing) xor1,2,4,8 tree.
    const int sj = ((j & 1) ? 8 : 0) ^ ((j & 2) ? 4 : 0)
                 ^ ((j & 4) ? 14 : 0) ^ ((j & 8) ? 3 : 0);

    // ereg[r] holds code (r ^ j)'s columns sj*4 .. sj*4+3 (select-free butterfly)
    float4 ereg[16];
    #pragma unroll
    for (int r = 0; r < 16; ++r)
        ereg[r] = *(const float4*)&s_emb[((r ^ j) * D_DIM) + sj * 4];
    const float se_j = s_se[j];           // lane j ends owning code k == j

    float lossacc = 0.f;

    const int gid    = (blockIdx.x * BLOCK + t) >> 4;   // global row-group id
    const int stride = (GRID * BLOCK) >> 4;             // 32768

    int row = gid;
    f32x4 zv = __builtin_nontemporal_load((const f32x4*)&z[(size_t)row * D_DIM + sj * 4]);

    while (row < B_ROWS) {
        // 1-deep prefetch of next row chunk (independent of the compute chain)
        const int nrow = row + stride;
        f32x4 zn = zv;
        if (nrow < B_ROWS)
            zn = __builtin_nontemporal_load((const f32x4*)&z[(size_t)nrow * D_DIM + sj * 4]);

        // partial dots; p[r] = partial for code (r ^ j) over this lane's 4 columns
        float p[16];
        #pragma unroll
        for (int r = 0; r < 16; ++r) {
            float4 e = ereg[r];
            p[r] = fmaf(zv.w, e.w, fmaf(zv.z, e.z, fmaf(zv.y, e.y, zv.x * e.x)));
        }

        // ||z||^2 partial + 16-lane all-reduce. Stage masks (1,2,7,15) with sigma
        // pair column-bits (3,2,1,0) — bitwise identical to round-0's (passing) tree.
        float szp = fmaf(zv.w, zv.w, fmaf(zv.z, zv.z, fmaf(zv.y, zv.y, zv.x * zv.x)));
        szp += xor1_dpp(szp);
        szp += xor2_dpp(szp);
        szp += xor7_dpp(szp);
        szp += xor15_dpp(szp);

        // select-free butterfly transpose-reduce, all-DPP, stage order (15,7,2,1):
        // invariant value(j,r) = partial of code r^j; stage m: p[r] += dpp_m(p[r^m]).
        #pragma unroll
        for (int r = 0; r < 8; ++r)  p[r] += xor15_dpp(p[15 - r]);
        #pragma unroll
        for (int r = 0; r < 4; ++r)  p[r] += xor7_dpp(p[7 - r]);
        p[0] += xor2_dpp(p[2]);
        p[1] += xor2_dpp(p[3]);
        p[0] += xor1_dpp(p[1]);
        const float dot = p[0];           // dot(z, e_j) at lane j

        // distance, f32-rounded exactly like ref: (||z||^2 + ||e_j||^2) - 2*dot
        const float d = (szp + se_j) - 2.0f * dot;

        // argmin over 16 lanes (exact min; order-free), first-occurrence tie-break
        float vmin = d;
        vmin = fminf(vmin, xor1_dpp(vmin));
        vmin = fminf(vmin, xor2_dpp(vmin));
        vmin = fminf(vmin, xor7_dpp(vmin));
        vmin = fminf(vmin, xor15_dpp(vmin));
        unsigned long long bal = __ballot(d == vmin);
        unsigned int mask = (unsigned int)((bal >> (t & 48)) & 0xFFFFull);
        int kmin = __ffs(mask) - 1;

        // quantized chunk from LDS embedding (the only DS op in the loop)
        const float4 qv = *(const float4*)&s_emb[kmin * D_DIM + sj * 4];

        // loss partial
        float dx = zv.x - qv.x; lossacc = fmaf(dx, dx, lossacc);
        dx = zv.y - qv.y;       lossacc = fmaf(dx, dx, lossacc);
        dx = zv.z - qv.z;       lossacc = fmaf(dx, dx, lossacc);
        dx = zv.w - qv.w;       lossacc = fmaf(dx, dx, lossacc);

        f32x4 qn = { qv.x, qv.y, qv.z, qv.w };
        __builtin_nontemporal_store(qn, (f32x4*)&out_q[(size_t)row * D_DIM + sj * 4]);
        if (j == 0) out_idx[row] = (float)kmin;

        zv  = zn;
        row = nrow;
    }

    // block loss reduction (deterministic)
    lossacc += __shfl_xor(lossacc, 32, 64);
    lossacc += __shfl_xor(lossacc, 16, 64);
    lossacc += __shfl_xor(lossacc, 8, 64);
    lossacc += __shfl_xor(lossacc, 4, 64);
    lossacc += __shfl_xor(lossacc, 2, 64);
    lossacc += __shfl_xor(lossacc, 1, 64);
    if ((t & 63) == 0) s_w[t >> 6] = lossacc;
    __syncthreads();
    if (t == 0) partials[blockIdx.x] = (s_w[0] + s_w[1]) + (s_w[2] + s_w[3]);
}

__global__ void vq_finalize(const float* __restrict__ partials, int n,
                            float* __restrict__ out_loss)
{
    __shared__ float sw[4];
    float s = 0.f;
    for (int i = threadIdx.x; i < n; i += 256) s += partials[i];
    s += __shfl_xor(s, 32, 64);
    s += __shfl_xor(s, 16, 64);
    s += __shfl_xor(s, 8, 64);
    s += __shfl_xor(s, 4, 64);
    s += __shfl_xor(s, 2, 64);
    s += __shfl_xor(s, 1, 64);
    if ((threadIdx.x & 63) == 0) sw[threadIdx.x >> 6] = s;
    __syncthreads();
    if (threadIdx.x == 0) {
        float tot = (sw[0] + sw[1]) + (sw[2] + sw[3]);
        // vq_loss = 1.25 * mean; 1.25 / 2^26 is exact in f32
        *out_loss = tot * (1.25f / (float)(B_ROWS * (size_t)D_DIM));
    }
}

extern "C" void kernel_launch(void* const* d_in, const int* in_sizes, int n_in,
                              void* d_out, int out_size, void* d_ws, size_t ws_size,
                              hipStream_t stream)
{
    const float* z   = (const float*)d_in[0];
    const float* emb = (const float*)d_in[1];
    float* out      = (float*)d_out;
    float* out_q    = out;                                  // [B,64]
    float* out_idx  = out + (size_t)B_ROWS * D_DIM;         // [B]
    float* out_loss = out_idx + B_ROWS;                     // [1]
    float* partials = (float*)d_ws;                         // GRID floats

    vq_main<<<GRID, BLOCK, 0, stream>>>(z, emb, out_q, out_idx, partials);
    vq_finalize<<<1, 256, 0, stream>>>(partials, GRID, out_loss);
}